// Round 14
// baseline (104.661 us; speedup 1.0000x reference)
//
#include <hip/hip_runtime.h>

#define NC      16
#define HW      (512 * 512)
#define NB      8
#define BPB     64                        // blocks per batch
#define NBLK    (NB * BPB)                // 512 blocks = 2 per CU
#define THREADS 512
#define PXR     512                       // pixels staged per round
#define ROUNDS  8                         // 4096 px per block
#define SMOOTH  1e-5f

// d_ws layout: P[v*NBLK+blk] for v in [0,34) (inter[c]/denom[c]/ce/pen
// partials, batch b = blk/BPB), then a 4-byte ticket counter at float
// offset 34*NBLK (zeroed via hipMemsetAsync each launch).
//
// Fusion rationale (r13): five distinct main-kernel schedules all plateau at
// ~4.3-4.7 TB/s effective read; the remaining non-read-path cost is the
// separate 1-block finalize kernel + launch gap (~5-7us serial). This fuses
// it via the last-block-done ticket (rocPRIM pattern): __threadfence() +
// device-scope atomicAdd; winner acquires and reduces P inline.
typedef __attribute__((address_space(3))) unsigned int       lds_u32;
typedef __attribute__((address_space(1))) const unsigned int glb_u32;

__device__ __forceinline__ void stage16(const float* g, float* l) {
    // lane i: 16B from g+16*i -> lds_base + 16*i (wave-uniform l, linear dest)
    __builtin_amdgcn_global_load_lds((glb_u32*)(const void*)g,
                                     (lds_u32*)(void*)l, 16, 0, 0);
}

__global__ __launch_bounds__(THREADS, 4) void domino_fused(
    const float* __restrict__ logits,   // [B, C, H, W]
    const int*   __restrict__ tgt,      // [B, H, W]
    const float* __restrict__ penalty,  // [C, C] row = target class
    float*       __restrict__ P,
    unsigned int* __restrict__ cnt,
    float*       __restrict__ out)
{
    __shared__ float bufA[NC * PXR];    // 32 KB, class-major buf[c*PXR+p]
    __shared__ float bufB[NC * PXR];    // 32 KB
    __shared__ float pen_t[NC * NC];    // pen_t[c*NC+t] = penalty[t*NC+c]
    __shared__ float red[8][34];
    __shared__ float dice_l[128], ce_l[8], pen_l[8], dice_w[2];
    __shared__ unsigned int winls;

    const int tid  = threadIdx.x;
    const int w    = tid >> 6;          // wave 0..7: stages classes 2w, 2w+1
    const int lane = tid & 63;
    const int b    = blockIdx.x / BPB;
    const int blk  = blockIdx.x % BPB;
    const int rot  = blockIdx.x & 7;    // round-order rotation (pixel-aligned)

    if (tid < NC * NC) {
        const int r = tid / NC, c = tid % NC;
        pen_t[c * NC + r] = penalty[tid];
    }

    const float* ob   = logits + (size_t)b * NC * HW;
    const int*   tb   = tgt    + (size_t)b * HW;
    const int    base = blk * (ROUNDS * PXR);
    const int    c0   = 2 * w, c1 = 2 * w + 1;
    const float* s0   = ob + (size_t)c0 * HW + base;
    const float* s1   = ob + (size_t)c1 * HW + base;

    // Prologue: stage chunk `rot` into bufA (4 async 1KB wave-instructions).
    {
        const int off = rot * PXR;
        stage16(s0 + off +   0 + lane * 4, &bufA[c0 * PXR +   0]);
        stage16(s0 + off + 256 + lane * 4, &bufA[c0 * PXR + 256]);
        stage16(s1 + off +   0 + lane * 4, &bufA[c1 * PXR +   0]);
        stage16(s1 + off + 256 + lane * 4, &bufA[c1 * PXR + 256]);
    }
    int tcur = tb[base + rot * PXR + tid];

    float inter_acc[NC], denom_acc[NC];
#pragma unroll
    for (int c = 0; c < NC; ++c) { inter_acc[c] = 0.f; denom_acc[c] = 0.f; }
    float ce_acc = 0.f, pen_acc = 0.f;

    __syncthreads();                    // drains vmcnt: bufA ready

    for (int r = 0; r < ROUNDS; ++r) {
        float* const curb = (r & 1) ? bufB : bufA;
        float* const nxtb = (r & 1) ? bufA : bufB;

        // 1) Issue next round's async loads straight into the other buffer.
        int tn = 0;
        if (r + 1 < ROUNDS) {
            const int off = ((r + 1 + rot) & 7) * PXR;
            stage16(s0 + off +   0 + lane * 4, &nxtb[c0 * PXR +   0]);
            stage16(s0 + off + 256 + lane * 4, &nxtb[c0 * PXR + 256]);
            stage16(s1 + off +   0 + lane * 4, &nxtb[c1 * PXR +   0]);
            stage16(s1 + off + 256 + lane * 4, &nxtb[c1 * PXR + 256]);
            tn = tb[base + off + tid];
        }

        // 2) Compute this round's pixel (p = tid) from LDS.
        //    curb[c*PXR+tid]: bank = tid%32 -> 2 lanes/bank = free.
        {
            const int t = tcur;
            float e[NC], s = 0.f;
#pragma unroll
            for (int c = 0; c < NC; ++c) {
                e[c] = __expf(curb[c * PXR + tid]);
                s += e[c];
            }
            float et = 0.f;
#pragma unroll
            for (int c = 0; c < NC; ++c) et = (t == c) ? e[c] : et;
            const float inv = 1.0f / s;
            ce_acc -= __logf(et * inv);
            float pdot = 0.f;
#pragma unroll
            for (int c = 0; c < NC; ++c) {
                const float p = e[c] * inv;
                denom_acc[c] += p + ((t == c) ? 1.f : 0.f);
                inter_acc[c] += (t == c) ? p : 0.f;
                pdot += pen_t[c * NC + t] * p;
            }
            pen_acc += pdot;
        }

        // 3) Barrier drains this wave's vmcnt (next buffer landed).
        __syncthreads();
        tcur = tn;
    }

    // Intra-wave butterfly reductions (64 lanes), then 8-wave fan-in.
#pragma unroll
    for (int c = 0; c < NC; ++c) {
#pragma unroll
        for (int off = 32; off; off >>= 1) {
            inter_acc[c] += __shfl_xor(inter_acc[c], off);
            denom_acc[c] += __shfl_xor(denom_acc[c], off);
        }
    }
#pragma unroll
    for (int off = 32; off; off >>= 1) {
        ce_acc  += __shfl_xor(ce_acc,  off);
        pen_acc += __shfl_xor(pen_acc, off);
    }

    if (lane == 0) {
#pragma unroll
        for (int c = 0; c < NC; ++c) {
            red[w][c]      = inter_acc[c];
            red[w][NC + c] = denom_acc[c];
        }
        red[w][32] = ce_acc;
        red[w][33] = pen_acc;
    }
    __syncthreads();

    if (tid < 34) {
        float v = 0.f;
#pragma unroll
        for (int i = 0; i < 8; ++i) v += red[i][tid];
        P[tid * NBLK + blockIdx.x] = v;
    }

    // ---- last-block-done ticket: winner block finalizes inline ----
    __threadfence();                    // release: P stores visible device-wide
    __syncthreads();
    if (tid == 0) {
        const unsigned int old = atomicAdd(cnt, 1u);   // device scope (m20)
        winls = (old == (unsigned)(NBLK - 1)) ? 1u : 0u;
    }
    __syncthreads();
    if (winls == 0u) return;
    __threadfence();                    // acquire: see all blocks' P stores

    // Finalize (512 threads): 4 threads per (c,b) dice bin (16 floats each),
    // plus 512-wide ce/pen reduction. Total read: 68 KB from L2.
    {
        const int bin = tid >> 2, j = tid & 3;   // bin in [0,128)
        const int c = bin >> 3, bb = bin & 7;

        const float* ip = P + (size_t)c        * NBLK + bb * BPB + j * 16;
        const float* dp = P + (size_t)(NC + c) * NBLK + bb * BPB + j * 16;
        float inter = 0.f, denom = 0.f;
#pragma unroll
        for (int k = 0; k < 4; ++k) {
            const float4 a = *(const float4*)(ip + 4 * k); inter += a.x + a.y + a.z + a.w;
            const float4 d = *(const float4*)(dp + 4 * k); denom += d.x + d.y + d.z + d.w;
        }
#pragma unroll
        for (int off = 2; off; off >>= 1) {
            inter += __shfl_xor(inter, off);
            denom += __shfl_xor(denom, off);
        }
        if (j == 0)
            dice_l[bin] = 1.0f - (2.0f * inter + SMOOTH) / (denom + SMOOTH);

        float ce  = P[32 * NBLK + tid];
        float pen = P[33 * NBLK + tid];
#pragma unroll
        for (int off = 32; off; off >>= 1) {
            ce  += __shfl_xor(ce,  off);
            pen += __shfl_xor(pen, off);
        }
        if (lane == 0) { ce_l[w] = ce; pen_l[w] = pen; }
        __syncthreads();

        if (tid < 128) {
            float d = dice_l[tid];
#pragma unroll
            for (int off = 32; off; off >>= 1) d += __shfl_xor(d, off);
            if ((tid & 63) == 0) dice_w[tid >> 6] = d;
        }
        __syncthreads();

        if (tid == 0) {
            float ces = 0.f, pens = 0.f;
#pragma unroll
            for (int i = 0; i < 8; ++i) { ces += ce_l[i]; pens += pen_l[i]; }
            out[0] = ces * (1.0f / (8.0f * 262144.0f))
                   + (dice_w[0] + dice_w[1]) * (1.0f / 128.0f)
                   + pens * (1.0f / 8.0f);
        }
    }
}

extern "C" void kernel_launch(void* const* d_in, const int* in_sizes, int n_in,
                              void* d_out, int out_size, void* d_ws, size_t ws_size,
                              hipStream_t stream)
{
    const float* logits = (const float*)d_in[0];   // [8,16,512,512] f32
    const int*   tgt    = (const int*)d_in[1];     // [8,1,512,512] int32
    const float* pen    = (const float*)d_in[2];   // [16,16] f32
    float*        P     = (float*)d_ws;
    unsigned int* cnt   = (unsigned int*)((char*)d_ws + 34 * NBLK * sizeof(float));
    float*        out   = (float*)d_out;

    (void)hipMemsetAsync(cnt, 0, sizeof(unsigned int), stream);   // ticket = 0
    domino_fused<<<NBLK, THREADS, 0, stream>>>(logits, tgt, pen, P, cnt, out);
}

// Round 15
// 48.436 us; speedup vs baseline: 2.1608x; 2.1608x over previous
//
#include <hip/hip_runtime.h>

#define NC      16
#define HW      (512 * 512)
#define NB      8
#define BPB     64                        // blocks per batch
#define NBLK    (NB * BPB)                // 512 blocks = 2 per CU
#define THREADS 512
#define PXR     512                       // pixels staged per round
#define ROUNDS  8                         // 4096 px per block
#define SMOOTH  1e-5f

// d_ws: P[v*NBLK+blk], v in [0,34) (inter[c]/denom[c]/ce/pen partials,
// batch b = blk/BPB) + 4-byte epoch ticket at float offset 34*NBLK.
//
// r14 lesson: __threadfence() on gfx950 = buffer_wbl2/inv L2 broadcasts;
// 4096 of them cost ~95us (kernel was 130us even fully cache-resident).
// This version is fence-free: P published via atomicExch (returning atomic
// = device-coherent store), ticket via epoch atomicAdd (winner =
// (old+1)%NBLK==0, no reset/memset needed, poison-safe), winner reads P
// via atomicAdd(p, 0.f) at the coherent point. No wbl2 anywhere.
typedef __attribute__((address_space(3))) unsigned int       lds_u32;
typedef __attribute__((address_space(1))) const unsigned int glb_u32;

__device__ __forceinline__ void stage16(const float* g, float* l) {
    // lane i: 16B from g+16*i -> lds_base + 16*i (wave-uniform l, linear dest)
    __builtin_amdgcn_global_load_lds((glb_u32*)(const void*)g,
                                     (lds_u32*)(void*)l, 16, 0, 0);
}

__global__ __launch_bounds__(THREADS, 4) void domino_fused(
    const float* __restrict__ logits,   // [B, C, H, W]
    const int*   __restrict__ tgt,      // [B, H, W]
    const float* __restrict__ penalty,  // [C, C] row = target class
    float*       __restrict__ P,
    unsigned int* __restrict__ cnt,
    float*       __restrict__ out)
{
    __shared__ float bufA[NC * PXR];    // 32 KB, class-major buf[c*PXR+p]
    __shared__ float bufB[NC * PXR];    // 32 KB
    __shared__ float pen_t[NC * NC];    // pen_t[c*NC+t] = penalty[t*NC+c]
    __shared__ float red[8][34];
    __shared__ float dice_l[128], ce_l[8], pen_l[8], dice_w[2];
    __shared__ unsigned int winls;

    const int tid  = threadIdx.x;
    const int w    = tid >> 6;          // wave 0..7: stages classes 2w, 2w+1
    const int lane = tid & 63;
    const int b    = blockIdx.x / BPB;
    const int blk  = blockIdx.x % BPB;
    const int rot  = blockIdx.x & 7;    // round-order rotation (pixel-aligned)

    if (tid < NC * NC) {
        const int r = tid / NC, c = tid % NC;
        pen_t[c * NC + r] = penalty[tid];
    }

    const float* ob   = logits + (size_t)b * NC * HW;
    const int*   tb   = tgt    + (size_t)b * HW;
    const int    base = blk * (ROUNDS * PXR);
    const int    c0   = 2 * w, c1 = 2 * w + 1;
    const float* s0   = ob + (size_t)c0 * HW + base;
    const float* s1   = ob + (size_t)c1 * HW + base;

    // Prologue: stage chunk `rot` into bufA (4 async 1KB wave-instructions).
    {
        const int off = rot * PXR;
        stage16(s0 + off +   0 + lane * 4, &bufA[c0 * PXR +   0]);
        stage16(s0 + off + 256 + lane * 4, &bufA[c0 * PXR + 256]);
        stage16(s1 + off +   0 + lane * 4, &bufA[c1 * PXR +   0]);
        stage16(s1 + off + 256 + lane * 4, &bufA[c1 * PXR + 256]);
    }
    int tcur = tb[base + rot * PXR + tid];

    float inter_acc[NC], denom_acc[NC];
#pragma unroll
    for (int c = 0; c < NC; ++c) { inter_acc[c] = 0.f; denom_acc[c] = 0.f; }
    float ce_acc = 0.f, pen_acc = 0.f;

    __syncthreads();                    // drains vmcnt: bufA ready

    for (int r = 0; r < ROUNDS; ++r) {
        float* const curb = (r & 1) ? bufB : bufA;
        float* const nxtb = (r & 1) ? bufA : bufB;

        // 1) Issue next round's async loads straight into the other buffer.
        int tn = 0;
        if (r + 1 < ROUNDS) {
            const int off = ((r + 1 + rot) & 7) * PXR;
            stage16(s0 + off +   0 + lane * 4, &nxtb[c0 * PXR +   0]);
            stage16(s0 + off + 256 + lane * 4, &nxtb[c0 * PXR + 256]);
            stage16(s1 + off +   0 + lane * 4, &nxtb[c1 * PXR +   0]);
            stage16(s1 + off + 256 + lane * 4, &nxtb[c1 * PXR + 256]);
            tn = tb[base + off + tid];
        }

        // 2) Compute this round's pixel (p = tid) from LDS.
        //    curb[c*PXR+tid]: bank = tid%32 -> 2 lanes/bank = free.
        {
            const int t = tcur;
            float e[NC], s = 0.f;
#pragma unroll
            for (int c = 0; c < NC; ++c) {
                e[c] = __expf(curb[c * PXR + tid]);
                s += e[c];
            }
            float et = 0.f;
#pragma unroll
            for (int c = 0; c < NC; ++c) et = (t == c) ? e[c] : et;
            const float inv = 1.0f / s;
            ce_acc -= __logf(et * inv);
            float pdot = 0.f;
#pragma unroll
            for (int c = 0; c < NC; ++c) {
                const float p = e[c] * inv;
                denom_acc[c] += p + ((t == c) ? 1.f : 0.f);
                inter_acc[c] += (t == c) ? p : 0.f;
                pdot += pen_t[c * NC + t] * p;
            }
            pen_acc += pdot;
        }

        // 3) Barrier drains this wave's vmcnt (next buffer landed).
        __syncthreads();
        tcur = tn;
    }

    // Intra-wave butterfly reductions (64 lanes), then 8-wave fan-in.
#pragma unroll
    for (int c = 0; c < NC; ++c) {
#pragma unroll
        for (int off = 32; off; off >>= 1) {
            inter_acc[c] += __shfl_xor(inter_acc[c], off);
            denom_acc[c] += __shfl_xor(denom_acc[c], off);
        }
    }
#pragma unroll
    for (int off = 32; off; off >>= 1) {
        ce_acc  += __shfl_xor(ce_acc,  off);
        pen_acc += __shfl_xor(pen_acc, off);
    }

    if (lane == 0) {
#pragma unroll
        for (int c = 0; c < NC; ++c) {
            red[w][c]      = inter_acc[c];
            red[w][NC + c] = denom_acc[c];
        }
        red[w][32] = ce_acc;
        red[w][33] = pen_acc;
    }
    __syncthreads();

    // Publish partials as device-coherent atomic stores (no fence needed).
    if (tid < 34) {
        float v = 0.f;
#pragma unroll
        for (int i = 0; i < 8; ++i) v += red[i][tid];
        (void)atomicExch(&P[tid * NBLK + blockIdx.x], v);
    }
    __syncthreads();                    // vmcnt(0): exchanges retired at LLC

    // Epoch ticket: 512 consecutive values contain exactly one multiple of
    // NBLK -> exactly one winner per launch, any starting cnt value.
    if (tid == 0) {
        const unsigned int old = atomicAdd(cnt, 1u);
        winls = ((old + 1u) % (unsigned)NBLK == 0u) ? 1u : 0u;
    }
    __syncthreads();
    if (winls == 0u) return;

    // Winner finalize (512 threads). Reads via atomic loads (coherent point).
    {
        const int bin = tid >> 2, j = tid & 3;   // bin in [0,128)
        const int c = bin >> 3, bb = bin & 7;

        float* ip = P + (size_t)c        * NBLK + bb * BPB + j * 16;
        float* dp = P + (size_t)(NC + c) * NBLK + bb * BPB + j * 16;
        float inter = 0.f, denom = 0.f;
#pragma unroll
        for (int k = 0; k < 16; ++k) {
            inter += atomicAdd(ip + k, 0.0f);
            denom += atomicAdd(dp + k, 0.0f);
        }
#pragma unroll
        for (int off = 2; off; off >>= 1) {
            inter += __shfl_xor(inter, off);
            denom += __shfl_xor(denom, off);
        }
        if (j == 0)
            dice_l[bin] = 1.0f - (2.0f * inter + SMOOTH) / (denom + SMOOTH);

        float ce  = atomicAdd(P + 32 * NBLK + tid, 0.0f);
        float pen = atomicAdd(P + 33 * NBLK + tid, 0.0f);
#pragma unroll
        for (int off = 32; off; off >>= 1) {
            ce  += __shfl_xor(ce,  off);
            pen += __shfl_xor(pen, off);
        }
        if (lane == 0) { ce_l[w] = ce; pen_l[w] = pen; }
        __syncthreads();

        if (tid < 128) {
            float d = dice_l[tid];
#pragma unroll
            for (int off = 32; off; off >>= 1) d += __shfl_xor(d, off);
            if ((tid & 63) == 0) dice_w[tid >> 6] = d;
        }
        __syncthreads();

        if (tid == 0) {
            float ces = 0.f, pens = 0.f;
#pragma unroll
            for (int i = 0; i < 8; ++i) { ces += ce_l[i]; pens += pen_l[i]; }
            out[0] = ces * (1.0f / (8.0f * 262144.0f))
                   + (dice_w[0] + dice_w[1]) * (1.0f / 128.0f)
                   + pens * (1.0f / 8.0f);
        }
    }
}

extern "C" void kernel_launch(void* const* d_in, const int* in_sizes, int n_in,
                              void* d_out, int out_size, void* d_ws, size_t ws_size,
                              hipStream_t stream)
{
    const float* logits = (const float*)d_in[0];   // [8,16,512,512] f32
    const int*   tgt    = (const int*)d_in[1];     // [8,1,512,512] int32
    const float* pen    = (const float*)d_in[2];   // [16,16] f32
    float*        P     = (float*)d_ws;
    unsigned int* cnt   = (unsigned int*)((char*)d_ws + 34 * NBLK * sizeof(float));
    float*        out   = (float*)d_out;

    domino_fused<<<NBLK, THREADS, 0, stream>>>(logits, tgt, pen, P, cnt, out);
}

// Round 16
// 38.710 us; speedup vs baseline: 2.7037x; 1.2512x over previous
//
#include <hip/hip_runtime.h>

#define NC      16
#define HW      (512 * 512)
#define NB      8
#define BPB     64                        // blocks per batch
#define NBLK    (NB * BPB)                // 512 blocks = 2 per CU
#define THREADS 512
#define PXR     512                       // pixels staged per round
#define ROUNDS  8                         // 4096 px per block
#define SMOOTH  1e-5f

// FINAL (r16 = r11, the measured best of 6 structural variants):
//  - global_load_lds async HBM->LDS double-buffer, 2 blocks/CU, rot-offset.
//  - Separate tiny finalize kernel (fusion measured SLOWER: r14 +66us fences,
//    r15 +10us ticket/atomic tail).
//  - Plateau evidence: 6 schedules in 38-44us ~= 4.3-4.7 TB/s effective read
//    with ideal bytes; in-flight depth already exceeds Little's-law need;
//    the 16-stream 1MiB-stride gather (forced by per-pixel softmax) is the
//    binding constraint, not scheduling, registers, or VALU.
typedef __attribute__((address_space(3))) unsigned int       lds_u32;
typedef __attribute__((address_space(1))) const unsigned int glb_u32;

__device__ __forceinline__ void stage16(const float* g, float* l) {
    // lane i: 16B from g+16*i -> lds_base + 16*i (wave-uniform l, linear dest)
    __builtin_amdgcn_global_load_lds((glb_u32*)(const void*)g,
                                     (lds_u32*)(void*)l, 16, 0, 0);
}

__global__ __launch_bounds__(THREADS, 4) void domino_main(
    const float* __restrict__ logits,   // [B, C, H, W]
    const int*   __restrict__ tgt,      // [B, H, W]
    const float* __restrict__ penalty,  // [C, C] row = target class
    float*       __restrict__ P)
{
    __shared__ float bufA[NC * PXR];    // 32 KB, class-major buf[c*PXR+p]
    __shared__ float bufB[NC * PXR];    // 32 KB
    __shared__ float pen_t[NC * NC];    // pen_t[c*NC+t] = penalty[t*NC+c]
    __shared__ float red[8][34];

    const int tid  = threadIdx.x;
    const int w    = tid >> 6;          // wave 0..7: stages classes 2w, 2w+1
    const int lane = tid & 63;
    const int b    = blockIdx.x / BPB;
    const int blk  = blockIdx.x % BPB;
    const int rot  = blockIdx.x & 7;    // round-order rotation (pixel-aligned)

    if (tid < NC * NC) {
        const int r = tid / NC, c = tid % NC;
        pen_t[c * NC + r] = penalty[tid];
    }

    const float* ob   = logits + (size_t)b * NC * HW;
    const int*   tb   = tgt    + (size_t)b * HW;
    const int    base = blk * (ROUNDS * PXR);
    const int    c0   = 2 * w, c1 = 2 * w + 1;
    const float* s0   = ob + (size_t)c0 * HW + base;
    const float* s1   = ob + (size_t)c1 * HW + base;

    // Prologue: stage chunk `rot` into bufA (4 async 1KB wave-instructions).
    {
        const int off = rot * PXR;
        stage16(s0 + off +   0 + lane * 4, &bufA[c0 * PXR +   0]);
        stage16(s0 + off + 256 + lane * 4, &bufA[c0 * PXR + 256]);
        stage16(s1 + off +   0 + lane * 4, &bufA[c1 * PXR +   0]);
        stage16(s1 + off + 256 + lane * 4, &bufA[c1 * PXR + 256]);
    }
    int tcur = tb[base + rot * PXR + tid];

    float inter_acc[NC], denom_acc[NC];
#pragma unroll
    for (int c = 0; c < NC; ++c) { inter_acc[c] = 0.f; denom_acc[c] = 0.f; }
    float ce_acc = 0.f, pen_acc = 0.f;

    __syncthreads();                    // drains vmcnt: bufA ready

    for (int r = 0; r < ROUNDS; ++r) {
        float* const curb = (r & 1) ? bufB : bufA;
        float* const nxtb = (r & 1) ? bufA : bufB;

        // 1) Issue next round's async loads straight into the other buffer.
        int tn = 0;
        if (r + 1 < ROUNDS) {
            const int off = ((r + 1 + rot) & 7) * PXR;
            stage16(s0 + off +   0 + lane * 4, &nxtb[c0 * PXR +   0]);
            stage16(s0 + off + 256 + lane * 4, &nxtb[c0 * PXR + 256]);
            stage16(s1 + off +   0 + lane * 4, &nxtb[c1 * PXR +   0]);
            stage16(s1 + off + 256 + lane * 4, &nxtb[c1 * PXR + 256]);
            tn = tb[base + off + tid];
        }

        // 2) Compute this round's pixel (p = tid) from LDS.
        //    curb[c*PXR+tid]: bank = tid%32 -> 2 lanes/bank = free.
        {
            const int t = tcur;
            float e[NC], s = 0.f;
#pragma unroll
            for (int c = 0; c < NC; ++c) {
                e[c] = __expf(curb[c * PXR + tid]);
                s += e[c];
            }
            float et = 0.f;
#pragma unroll
            for (int c = 0; c < NC; ++c) et = (t == c) ? e[c] : et;
            const float inv = 1.0f / s;
            ce_acc -= __logf(et * inv);
            float pdot = 0.f;
#pragma unroll
            for (int c = 0; c < NC; ++c) {
                const float p = e[c] * inv;
                denom_acc[c] += p + ((t == c) ? 1.f : 0.f);
                inter_acc[c] += (t == c) ? p : 0.f;
                pdot += pen_t[c * NC + t] * p;
            }
            pen_acc += pdot;
        }

        // 3) Barrier drains this wave's vmcnt (next buffer landed); the
        //    co-resident block computes during our drain.
        __syncthreads();
        tcur = tn;
    }

    // Intra-wave butterfly reductions (64 lanes), then 8-wave fan-in.
#pragma unroll
    for (int c = 0; c < NC; ++c) {
#pragma unroll
        for (int off = 32; off; off >>= 1) {
            inter_acc[c] += __shfl_xor(inter_acc[c], off);
            denom_acc[c] += __shfl_xor(denom_acc[c], off);
        }
    }
#pragma unroll
    for (int off = 32; off; off >>= 1) {
        ce_acc  += __shfl_xor(ce_acc,  off);
        pen_acc += __shfl_xor(pen_acc, off);
    }

    if (lane == 0) {
#pragma unroll
        for (int c = 0; c < NC; ++c) {
            red[w][c]      = inter_acc[c];
            red[w][NC + c] = denom_acc[c];
        }
        red[w][32] = ce_acc;
        red[w][33] = pen_acc;
    }
    __syncthreads();

    if (tid < 34) {
        float v = 0.f;
#pragma unroll
        for (int i = 0; i < 8; ++i) v += red[i][tid];
        P[tid * NBLK + blockIdx.x] = v;
    }
}

// One block, 512 threads: 4 threads per (c,b) dice bin (16 floats each),
// plus 512-wide ce/pen reduction. Total read: 68 KB.
__global__ __launch_bounds__(512) void domino_final(
    const float* __restrict__ P, float* __restrict__ out)
{
    __shared__ float dice_l[128], ce_l[8], pen_l[8], dice_w[2];

    const int tid = threadIdx.x;
    const int bin = tid >> 2, j = tid & 3;   // bin in [0,128)
    const int c = bin >> 3, bb = bin & 7;

    const float* ip = P + (size_t)c        * NBLK + bb * BPB + j * 16;
    const float* dp = P + (size_t)(NC + c) * NBLK + bb * BPB + j * 16;
    float inter = 0.f, denom = 0.f;
#pragma unroll
    for (int k = 0; k < 4; ++k) {
        const float4 a = *(const float4*)(ip + 4 * k); inter += a.x + a.y + a.z + a.w;
        const float4 d = *(const float4*)(dp + 4 * k); denom += d.x + d.y + d.z + d.w;
    }
#pragma unroll
    for (int off = 2; off; off >>= 1) {
        inter += __shfl_xor(inter, off);
        denom += __shfl_xor(denom, off);
    }
    if (j == 0)
        dice_l[bin] = 1.0f - (2.0f * inter + SMOOTH) / (denom + SMOOTH);

    float ce  = P[32 * NBLK + tid];
    float pen = P[33 * NBLK + tid];
#pragma unroll
    for (int off = 32; off; off >>= 1) {
        ce  += __shfl_xor(ce,  off);
        pen += __shfl_xor(pen, off);
    }
    const int lane = tid & 63, wid = tid >> 6;
    if (lane == 0) { ce_l[wid] = ce; pen_l[wid] = pen; }
    __syncthreads();

    if (tid < 128) {
        float d = dice_l[tid];
#pragma unroll
        for (int off = 32; off; off >>= 1) d += __shfl_xor(d, off);
        if ((tid & 63) == 0) dice_w[tid >> 6] = d;
    }
    __syncthreads();

    if (tid == 0) {
        float ces = 0.f, pens = 0.f;
#pragma unroll
        for (int i = 0; i < 8; ++i) { ces += ce_l[i]; pens += pen_l[i]; }
        out[0] = ces * (1.0f / (8.0f * 262144.0f))
               + (dice_w[0] + dice_w[1]) * (1.0f / 128.0f)
               + pens * (1.0f / 8.0f);
    }
}

extern "C" void kernel_launch(void* const* d_in, const int* in_sizes, int n_in,
                              void* d_out, int out_size, void* d_ws, size_t ws_size,
                              hipStream_t stream)
{
    const float* logits = (const float*)d_in[0];   // [8,16,512,512] f32
    const int*   tgt    = (const int*)d_in[1];     // [8,1,512,512] int32
    const float* pen    = (const float*)d_in[2];   // [16,16] f32
    float*       P      = (float*)d_ws;
    float*       out    = (float*)d_out;

    domino_main<<<NBLK, THREADS, 0, stream>>>(logits, tgt, pen, P);
    domino_final<<<1, 512, 0, stream>>>(P, out);
}